// Round 14
// baseline (435.039 us; speedup 1.0000x reference)
//
#include <hip/hip_runtime.h>
#include <hip/hip_bf16.h>
#include <stdint.h>

#define HID    128
#define DT     0.1f
#define NITER  10
#define NTHR   512          // 8 waves per block
#define NW     8
#define NBLK   512          // 2 blocks per CU (LDS 76.3 KB x2 fits 160 KiB)
#define NCH    2            // 512*8*2*32 = 262144 rows
#define SCALE  2.885390081777927f   // 2*log2(e) folded into W1..3/b1..3

typedef __attribute__((ext_vector_type(8))) short bf16x8;   // MFMA A/B frag
typedef __attribute__((ext_vector_type(4))) float f32x4;    // MFMA C/D frag
typedef __attribute__((ext_vector_type(2))) unsigned int u32x2;
typedef __attribute__((ext_vector_type(4))) unsigned int u32x4;

union FragU { bf16x8 v; uint32_t u[4]; };

// LDS: ONLY shared read-only weights + tiny kk scratch. Activations never
// touch LDS. W1 stored COMPACT (only the g==0 quarter is nonzero) to get
// total LDS under 80 KiB -> 2 blocks/CU -> 4 waves/SIMD.
struct alignas(16) Smem {
    uint32_t w2f[8 * 4 * 64 * 4];   // 32 KB  [(ot*4+kt)*64+lane][4 u32], phi-permuted k
    uint32_t w3f[8 * 4 * 64 * 4];   // 32 KB  phi-permuted k
    uint32_t w1c[8 * 16 * 2];       //  1 KB  compact W1: [ot*16+ln][2 u32]
    uint32_t w4l[4 * 64 * 4];       //  4 KB  [kt*64+lane][4 u32], phi-permuted k
    float    b1[HID], b2[HID], b3[HID];   // 1.5 KB, pre-scaled
    float    kk[NW * 32 * 4];       //  4 KB  per-wave K scratch for final combine
};  // 76288 B -> 2 blocks/CU

__device__ __forceinline__ uint16_t f2bf(float f) {
    uint32_t u = __float_as_uint(f);
    return (uint16_t)((u + 0x7fffu + ((u >> 16) & 1u)) >> 16);
}

__device__ __forceinline__ uint32_t pk2(float a, float b) {
    __hip_bfloat162 h = __float22bfloat162_rn(float2{a, b});
    return *reinterpret_cast<uint32_t*>(&h);
}

// 4x tanh with ONE v_rcp via batched (Montgomery) inversion: 4 exp2 + 1 rcp
// = 80 trans-cyc per 4 tanh vs 128 for the scalar form (trans pipe is the
// measured bottleneck, round 13). Inputs y = 2*log2(e)*x (scale pre-folded).
// Clamp y<=30: 4-product <= 2^120 finite, rcp normal. Validated round 4
// (harness passed, absmax unchanged).
__device__ __forceinline__ f32x4 tanh4(f32x4 y) {
    float e0 = __builtin_amdgcn_exp2f(fminf(y[0], 30.f)) + 1.0f;
    float e1 = __builtin_amdgcn_exp2f(fminf(y[1], 30.f)) + 1.0f;
    float e2 = __builtin_amdgcn_exp2f(fminf(y[2], 30.f)) + 1.0f;
    float e3 = __builtin_amdgcn_exp2f(fminf(y[3], 30.f)) + 1.0f;
    float p01   = e0 * e1;
    float p012  = p01 * e2;
    float p0123 = p012 * e3;
    float r     = __builtin_amdgcn_rcpf(p0123);
    float i3   = p012 * r;        // 1/e3
    float r012 = e3 * r;          // 1/(e0*e1*e2)
    float i2   = p01 * r012;      // 1/e2
    float r01  = e2 * r012;       // 1/(e0*e1)
    float i1   = e0 * r01;        // 1/e1
    float i0   = e1 * r01;        // 1/e0
    return (f32x4){fmaf(-2.f, i0, 1.f), fmaf(-2.f, i1, 1.f),
                   fmaf(-2.f, i2, 1.f), fmaf(-2.f, i3, 1.f)};
}

__device__ __forceinline__ float uread(const float* p) {
    return __uint_as_float(__builtin_amdgcn_readfirstlane(__float_as_uint(*p)));
}

// Pack two D-accs into the next layer's k-frag op under the phi permutation:
// frag elem j = feature 16*(2op+(j>>2)) + 4g + (j&3).
__device__ __forceinline__ bf16x8 pack2(const f32x4& a0, const f32x4& a1) {
    f32x4 t0 = tanh4(a0);
    f32x4 t1 = tanh4(a1);
    FragU f;
    f.u[0] = pk2(t0[0], t0[1]);
    f.u[1] = pk2(t0[2], t0[3]);
    f.u[2] = pk2(t1[0], t1[1]);
    f.u[3] = pk2(t1[2], t1[3]);
    return f.v;
}

// One dense layer for this wave's 32 rows (2 n-tiles), register-resident,
// 4 output-pair passes; each weight b128 read feeds both tiles. zz is the
// asm-laundered zero keeping LDS addresses loop-variant so LICM can't hoist
// weights into long-lived regs (spill fix proven in round 12: VGPR 128->52).
__device__ __forceinline__ void dense_reg(
    const uint32_t* __restrict__ wf, const float* __restrict__ bias,
    bf16x8 (&bfrA)[4], bf16x8 (&bfrB)[4], int lane, int g, uint32_t zz)
{
    bf16x8 nA[4], nB[4];
    #pragma unroll
    for (int op = 0; op < 4; ++op) {
        f32x4 b0 = *(const f32x4*)&bias[(2 * op) * 16 + 4 * g + zz];
        f32x4 b1 = *(const f32x4*)&bias[(2 * op + 1) * 16 + 4 * g + zz];
        f32x4 a0A = b0, a0B = b0, a1A = b1, a1B = b1;
        __builtin_amdgcn_s_setprio(1);
        #pragma unroll
        for (int kt = 0; kt < 4; ++kt) {
            bf16x8 w0 = *(const bf16x8*)&wf[(((2 * op) * 4 + kt) * 64 + lane) * 4 + zz];
            a0A = __builtin_amdgcn_mfma_f32_16x16x32_bf16(w0, bfrA[kt], a0A, 0, 0, 0);
            a0B = __builtin_amdgcn_mfma_f32_16x16x32_bf16(w0, bfrB[kt], a0B, 0, 0, 0);
        }
        #pragma unroll
        for (int kt = 0; kt < 4; ++kt) {
            bf16x8 w1 = *(const bf16x8*)&wf[(((2 * op + 1) * 4 + kt) * 64 + lane) * 4 + zz];
            a1A = __builtin_amdgcn_mfma_f32_16x16x32_bf16(w1, bfrA[kt], a1A, 0, 0, 0);
            a1B = __builtin_amdgcn_mfma_f32_16x16x32_bf16(w1, bfrB[kt], a1B, 0, 0, 0);
        }
        __builtin_amdgcn_s_setprio(0);
        nA[op] = pack2(a0A, a1A);
        nB[op] = pack2(a0B, a1B);
    }
    #pragma unroll
    for (int kt = 0; kt < 4; ++kt) { bfrA[kt] = nA[kt]; bfrB[kt] = nB[kt]; }
}

__global__ __launch_bounds__(NTHR, 1) void pinn_irk_reg(
    const float* __restrict__ x0g,
    const float* __restrict__ w1g, const float* __restrict__ b1g,
    const float* __restrict__ w2g, const float* __restrict__ b2g,
    const float* __restrict__ w3g, const float* __restrict__ b3g,
    const float* __restrict__ w4g, const float* __restrict__ b4g,
    const float* __restrict__ l1g, const float* __restrict__ l2g,
    const float* __restrict__ l3g, const float* __restrict__ l4g,
    const float* __restrict__ alg, const float* __restrict__ beg,
    float* __restrict__ outg)
{
    __shared__ Smem S;
    const int t    = threadIdx.x;
    const int blk  = blockIdx.x;
    const int lane = t & 63;
    const int w    = t >> 6;
    const int ln   = lane & 15;
    const int g    = lane >> 4;
    const bool owner = (g == 0);    // lane (ln,0) owns rows base+ln, base+16+ln

    // ---- uniform params -> SGPRs ----
    const float L0 = uread(l1g), L1v = uread(l2g), L2v = uread(l3g), L3v = uread(l4g);
    const float B40 = uread(b4g), B41 = uread(b4g + 1);
    const float B42 = uread(b4g + 2), B43 = uread(b4g + 3);
    const float BE0 = uread(beg), BE1 = uread(beg + 1);
    const float BE2 = uread(beg + 2), BE3 = uread(beg + 3);
    float A[16];
    #pragma unroll
    for (int i = 0; i < 16; ++i) A[i] = uread(alg + i);

    // ---- stage W2/W3 fragments, phi-permuted k:
    //      slot (g,kt,j) multiplies feature k' = 16*(2kt+(j>>2)) + 4g + (j&3)
    for (int s = t; s < 2048; s += NTHR) {
        int lane_s = s & 63, kto = s >> 6;
        int kt = kto & 3, ot = kto >> 2;
        int m = ot * 16 + (lane_s & 15), gs = lane_s >> 4;
        uint32_t f2[4], f3[4];
        #pragma unroll
        for (int jj = 0; jj < 4; ++jj) {
            int k = 16 * (2 * kt + (jj >> 1)) + 4 * gs + 2 * (jj & 1);
            f2[jj] = (uint32_t)f2bf(w2g[k * HID + m] * SCALE)
                   | ((uint32_t)f2bf(w2g[(k + 1) * HID + m] * SCALE) << 16);
            f3[jj] = (uint32_t)f2bf(w3g[k * HID + m] * SCALE)
                   | ((uint32_t)f2bf(w3g[(k + 1) * HID + m] * SCALE) << 16);
        }
        *(u32x4*)&S.w2f[s * 4] = (u32x4){f2[0], f2[1], f2[2], f2[3]};
        *(u32x4*)&S.w3f[s * 4] = (u32x4){f3[0], f3[1], f3[2], f3[3]};
    }
    // ---- stage compact W1: [ot*16+ln] -> {W1[0..1][m], W1[2..3][m]} ----
    if (t < 128) {
        int ot = t >> 4, lns = t & 15;
        int m = ot * 16 + lns;
        S.w1c[t * 2]     = (uint32_t)f2bf(w1g[0 * HID + m] * SCALE)
                         | ((uint32_t)f2bf(w1g[1 * HID + m] * SCALE) << 16);
        S.w1c[t * 2 + 1] = (uint32_t)f2bf(w1g[2 * HID + m] * SCALE)
                         | ((uint32_t)f2bf(w1g[3 * HID + m] * SCALE) << 16);
    }
    // ---- stage W4^T A-frags -> LDS [kt*64+lane], phi-permuted k ----
    if (t < 256) {
        int lane_s = t & 63, kt = t >> 6;
        int lns = lane_s & 15, gs = lane_s >> 4;
        uint32_t f[4];
        #pragma unroll
        for (int jj = 0; jj < 4; ++jj) {
            int k0 = 16 * (2 * kt + (jj >> 1)) + 4 * gs + 2 * (jj & 1);
            uint32_t lo = (lns < 4) ? (uint32_t)f2bf(w4g[k0 * 4 + lns]) : 0u;
            uint32_t hi = (lns < 4) ? (uint32_t)f2bf(w4g[(k0 + 1) * 4 + lns]) : 0u;
            f[jj] = lo | (hi << 16);
        }
        *(u32x4*)&S.w4l[t * 4] = (u32x4){f[0], f[1], f[2], f[3]};
    }
    if (t < HID) {
        S.b1[t] = b1g[t] * SCALE;
        S.b2[t] = b2g[t] * SCALE;
        S.b3[t] = b3g[t] * SCALE;
    }
    __syncthreads();   // the ONLY block-wide barrier

    for (int ch = 0; ch < NCH; ++ch) {
        const int base = ((blk * NW + w) * NCH + ch) * 32;
        // X0 of owner rows (all lanes load; only g==0 values matter)
        f32x4 XA0 = *(const f32x4*)&x0g[((base + ln) >> 2) * 4];
        f32x4 XB0 = *(const f32x4*)&x0g[((base + 16 + ln) >> 2) * 4];
        f32x4 XA = XA0, XB = XB0;
        float* kkw = &S.kk[w * 128];

        #pragma unroll 1
        for (int it = 0; it < NITER; ++it) {
            // ---- anti-hoist: opaque zero, re-defined every iteration ----
            uint32_t zz = 0;
            asm volatile("" : "+v"(zz));
            zz &= ~3u;   // multiple of 4 u32 = 16B: aligns b128 and b64 reads

            // ---- X -> B-frags (k=0..3 real; non-owner slots hit zero weights)
            FragU xa, xb;
            xa.u[0] = owner ? pk2(XA[0], XA[1]) : 0u;
            xa.u[1] = owner ? pk2(XA[2], XA[3]) : 0u;
            xa.u[2] = 0u; xa.u[3] = 0u;
            xb.u[0] = owner ? pk2(XB[0], XB[1]) : 0u;
            xb.u[1] = owner ? pk2(XB[2], XB[3]) : 0u;
            xb.u[2] = 0u; xb.u[3] = 0u;

            // ---- L1: compact-W1 frags (nonzero only on g==0) -> MFMA -> pack
            bf16x8 bfrA[4], bfrB[4];
            #pragma unroll
            for (int op = 0; op < 4; ++op) {
                f32x4 b0 = *(const f32x4*)&S.b1[(2 * op) * 16 + 4 * g + zz];
                f32x4 b1 = *(const f32x4*)&S.b1[(2 * op + 1) * 16 + 4 * g + zz];
                u32x2 c0 = *(const u32x2*)&S.w1c[((2 * op) * 16 + ln) * 2 + zz];
                u32x2 c1 = *(const u32x2*)&S.w1c[((2 * op + 1) * 16 + ln) * 2 + zz];
                FragU w0f, w1f;
                w0f.u[0] = owner ? c0.x : 0u; w0f.u[1] = owner ? c0.y : 0u;
                w0f.u[2] = 0u; w0f.u[3] = 0u;
                w1f.u[0] = owner ? c1.x : 0u; w1f.u[1] = owner ? c1.y : 0u;
                w1f.u[2] = 0u; w1f.u[3] = 0u;
                f32x4 a0A = __builtin_amdgcn_mfma_f32_16x16x32_bf16(w0f.v, xa.v, b0, 0, 0, 0);
                f32x4 a0B = __builtin_amdgcn_mfma_f32_16x16x32_bf16(w0f.v, xb.v, b0, 0, 0, 0);
                f32x4 a1A = __builtin_amdgcn_mfma_f32_16x16x32_bf16(w1f.v, xa.v, b1, 0, 0, 0);
                f32x4 a1B = __builtin_amdgcn_mfma_f32_16x16x32_bf16(w1f.v, xb.v, b1, 0, 0, 0);
                bfrA[op] = pack2(a0A, a1A);
                bfrB[op] = pack2(a0B, a1B);
            }

            // ---- L2, L3 (register-resident chain, weights streamed) ----
            dense_reg(S.w2f, S.b2, bfrA, bfrB, lane, g, zz);
            dense_reg(S.w3f, S.b3, bfrA, bfrB, lane, g, zz);

            // ---- L4 + K + X update (W4 frags from LDS) ----
            f32x4 kA = {0.f, 0.f, 0.f, 0.f}, kB = {0.f, 0.f, 0.f, 0.f};
            __builtin_amdgcn_s_setprio(1);
            #pragma unroll
            for (int kt = 0; kt < 4; ++kt) {
                bf16x8 wfr = *(const bf16x8*)&S.w4l[(kt * 64 + lane) * 4 + zz];
                kA = __builtin_amdgcn_mfma_f32_16x16x32_bf16(wfr, bfrA[kt], kA, 0, 0, 0);
                kB = __builtin_amdgcn_mfma_f32_16x16x32_bf16(wfr, bfrB[kt], kB, 0, 0, 0);
            }
            __builtin_amdgcn_s_setprio(0);
            // owner lanes (g==0) hold K[row][0..3]; kv written to LDS each
            // iter (last one persists) so it's not live across iterations.
            {
                float h0 = kA[0] + B40, h1 = kA[1] + B41;
                float h2 = kA[2] + B42, h3 = kA[3] + B43;
                f32x4 kvA = (f32x4){-L0 * h2 - L1v * XA[2], -L0 * h3 - L1v * XA[3],
                                     L2v * h0 + L3v * XA[0],  L2v * h1 + L3v * XA[1]};
                h0 = kB[0] + B40; h1 = kB[1] + B41;
                h2 = kB[2] + B42; h3 = kB[3] + B43;
                f32x4 kvB = (f32x4){-L0 * h2 - L1v * XB[2], -L0 * h3 - L1v * XB[3],
                                     L2v * h0 + L3v * XB[0],  L2v * h1 + L3v * XB[1]};
                if (owner) {
                    *(f32x4*)&kkw[ln * 4]        = kvA;
                    *(f32x4*)&kkw[(16 + ln) * 4] = kvB;
                }
                #pragma unroll
                for (int c = 0; c < 4; ++c) {
                    float sA = kvA[0] * A[c] + kvA[1] * A[4 + c]
                             + kvA[2] * A[8 + c] + kvA[3] * A[12 + c];
                    float sB = kvB[0] * A[c] + kvB[1] * A[4 + c]
                             + kvB[2] * A[8 + c] + kvB[3] * A[12 + c];
                    XA[c] = fmaf(DT, sA, XA0[c]);
                    XB[c] = fmaf(DT, sB, XB0[c]);
                }
            }
        }

        // ---- final combine via per-wave kk scratch ----
        // per-wave in-order DS + compiler lgkmcnt make the reads safe
        if (lane < 32) {
            int bl_ = lane >> 2, i = lane & 3;
            float s = BE0 * kkw[(bl_ * 4 + 0) * 4 + i]
                    + BE1 * kkw[(bl_ * 4 + 1) * 4 + i]
                    + BE2 * kkw[(bl_ * 4 + 2) * 4 + i]
                    + BE3 * kkw[(bl_ * 4 + 3) * 4 + i];
            int idx = base + lane;
            outg[idx] = x0g[idx] + DT * s;
        }
    }
}

extern "C" void kernel_launch(void* const* d_in, const int* in_sizes, int n_in,
                              void* d_out, int out_size, void* d_ws, size_t ws_size,
                              hipStream_t stream) {
    (void)in_sizes; (void)n_in; (void)d_ws; (void)ws_size; (void)out_size;

    dim3 grid(NBLK);    // 2 blocks per CU (LDS-limited); 4 waves/SIMD
    dim3 block(NTHR);

    pinn_irk_reg<<<grid, block, 0, stream>>>(
        (const float*)d_in[0],
        (const float*)d_in[1],  (const float*)d_in[2],
        (const float*)d_in[3],  (const float*)d_in[4],
        (const float*)d_in[5],  (const float*)d_in[6],
        (const float*)d_in[7],  (const float*)d_in[8],
        (const float*)d_in[9],  (const float*)d_in[10],
        (const float*)d_in[11], (const float*)d_in[12],
        (const float*)d_in[13], (const float*)d_in[14],
        (float*)d_out);
}

// Round 15
// 362.189 us; speedup vs baseline: 1.2011x; 1.2011x over previous
//
#include <hip/hip_runtime.h>
#include <hip/hip_bf16.h>
#include <stdint.h>

#define HID    128
#define DT     0.1f
#define NITER  10
#define NTHR   1024         // 16 waves per block
#define NW     16
#define NBLK   512          // 2 blocks/CU -> 32 waves/CU = 8 waves/SIMD
#define NCH    1            // 512*16*1*32 = 262144 rows
#define SCALE  2.885390081777927f   // 2*log2(e) folded into W1..3/b1..3

typedef __attribute__((ext_vector_type(8))) short bf16x8;   // MFMA A/B frag
typedef __attribute__((ext_vector_type(4))) float f32x4;    // MFMA C/D frag
typedef __attribute__((ext_vector_type(2))) unsigned int u32x2;
typedef __attribute__((ext_vector_type(4))) unsigned int u32x4;

union FragU { bf16x8 v; uint32_t u[4]; };

// LDS: ONLY shared read-only weights + kk scratch. Activations never touch
// LDS. 80384 B/block -> exactly 2 blocks per 160 KiB CU.
struct alignas(16) Smem {
    uint32_t w2f[8 * 4 * 64 * 4];   // 32 KB  [(ot*4+kt)*64+lane][4 u32], phi-permuted k
    uint32_t w3f[8 * 4 * 64 * 4];   // 32 KB  phi-permuted k
    uint32_t w1c[8 * 16 * 2];       //  1 KB  compact W1: [ot*16+ln][2 u32]
    uint32_t w4l[4 * 64 * 4];       //  4 KB  [kt*64+lane][4 u32], phi-permuted k
    float    b1[HID], b2[HID], b3[HID];   // 1.5 KB, pre-scaled
    float    kk[NW * 32 * 4];       //  8 KB  per-wave K scratch for final combine
};  // 80384 B

__device__ __forceinline__ uint16_t f2bf(float f) {
    uint32_t u = __float_as_uint(f);
    return (uint16_t)((u + 0x7fffu + ((u >> 16) & 1u)) >> 16);
}

__device__ __forceinline__ uint32_t pk2(float a, float b) {
    __hip_bfloat162 h = __float22bfloat162_rn(float2{a, b});
    return *reinterpret_cast<uint32_t*>(&h);
}

// y = 2*log2(e)*x already (scale folded into W/b): tanh(x) = 1 - 2/(2^y+1).
// Scalar form is optimal: trans ops are fully pipelined at ~4 cyc/wave64
// (round-14 calibration: tanh4's 21 full-rate ops lost to this 8-trans form).
__device__ __forceinline__ float tanh_pre(float y) {
    float e = __builtin_amdgcn_exp2f(y);
    return fmaf(-2.0f, __builtin_amdgcn_rcpf(e + 1.0f), 1.0f);
}

__device__ __forceinline__ float uread(const float* p) {
    return __uint_as_float(__builtin_amdgcn_readfirstlane(__float_as_uint(*p)));
}

// Pack two D-accs into the next layer's k-frag op under the phi permutation:
// frag elem j = feature 16*(2op+(j>>2)) + 4g + (j&3).
__device__ __forceinline__ bf16x8 pack2(const f32x4& a0, const f32x4& a1) {
    FragU f;
    f.u[0] = pk2(tanh_pre(a0[0]), tanh_pre(a0[1]));
    f.u[1] = pk2(tanh_pre(a0[2]), tanh_pre(a0[3]));
    f.u[2] = pk2(tanh_pre(a1[0]), tanh_pre(a1[1]));
    f.u[3] = pk2(tanh_pre(a1[2]), tanh_pre(a1[3]));
    return f.v;
}

// One dense layer for this wave's 32 rows (2 n-tiles), register-resident,
// 4 output-pair passes; each weight b128 read feeds both tiles. zz is the
// asm-laundered zero keeping LDS addresses loop-variant so LICM can't hoist
// weights into long-lived regs (spill fix proven in round 12: VGPR 128->52).
__device__ __forceinline__ void dense_reg(
    const uint32_t* __restrict__ wf, const float* __restrict__ bias,
    bf16x8 (&bfrA)[4], bf16x8 (&bfrB)[4], int lane, int g, uint32_t zz)
{
    bf16x8 nA[4], nB[4];
    #pragma unroll
    for (int op = 0; op < 4; ++op) {
        f32x4 b0 = *(const f32x4*)&bias[(2 * op) * 16 + 4 * g + zz];
        f32x4 b1 = *(const f32x4*)&bias[(2 * op + 1) * 16 + 4 * g + zz];
        f32x4 a0A = b0, a0B = b0, a1A = b1, a1B = b1;
        __builtin_amdgcn_s_setprio(1);
        #pragma unroll
        for (int kt = 0; kt < 4; ++kt) {
            bf16x8 w0 = *(const bf16x8*)&wf[(((2 * op) * 4 + kt) * 64 + lane) * 4 + zz];
            a0A = __builtin_amdgcn_mfma_f32_16x16x32_bf16(w0, bfrA[kt], a0A, 0, 0, 0);
            a0B = __builtin_amdgcn_mfma_f32_16x16x32_bf16(w0, bfrB[kt], a0B, 0, 0, 0);
        }
        #pragma unroll
        for (int kt = 0; kt < 4; ++kt) {
            bf16x8 w1 = *(const bf16x8*)&wf[(((2 * op + 1) * 4 + kt) * 64 + lane) * 4 + zz];
            a1A = __builtin_amdgcn_mfma_f32_16x16x32_bf16(w1, bfrA[kt], a1A, 0, 0, 0);
            a1B = __builtin_amdgcn_mfma_f32_16x16x32_bf16(w1, bfrB[kt], a1B, 0, 0, 0);
        }
        __builtin_amdgcn_s_setprio(0);
        nA[op] = pack2(a0A, a1A);
        nB[op] = pack2(a0B, a1B);
    }
    #pragma unroll
    for (int kt = 0; kt < 4; ++kt) { bfrA[kt] = nA[kt]; bfrB[kt] = nB[kt]; }
}

__global__ __launch_bounds__(NTHR, 1) void pinn_irk_reg(
    const float* __restrict__ x0g,
    const float* __restrict__ w1g, const float* __restrict__ b1g,
    const float* __restrict__ w2g, const float* __restrict__ b2g,
    const float* __restrict__ w3g, const float* __restrict__ b3g,
    const float* __restrict__ w4g, const float* __restrict__ b4g,
    const float* __restrict__ l1g, const float* __restrict__ l2g,
    const float* __restrict__ l3g, const float* __restrict__ l4g,
    const float* __restrict__ alg, const float* __restrict__ beg,
    float* __restrict__ outg)
{
    __shared__ Smem S;
    const int t    = threadIdx.x;
    const int blk  = blockIdx.x;
    const int lane = t & 63;
    const int w    = t >> 6;
    const int ln   = lane & 15;
    const int g    = lane >> 4;
    const bool owner = (g == 0);    // lane (ln,0) owns rows base+ln, base+16+ln

    // ---- uniform params -> SGPRs ----
    const float L0 = uread(l1g), L1v = uread(l2g), L2v = uread(l3g), L3v = uread(l4g);
    const float B40 = uread(b4g), B41 = uread(b4g + 1);
    const float B42 = uread(b4g + 2), B43 = uread(b4g + 3);
    const float BE0 = uread(beg), BE1 = uread(beg + 1);
    const float BE2 = uread(beg + 2), BE3 = uread(beg + 3);
    float A[16];
    #pragma unroll
    for (int i = 0; i < 16; ++i) A[i] = uread(alg + i);

    // ---- stage W2/W3 fragments, phi-permuted k:
    //      slot (g,kt,j) multiplies feature k' = 16*(2kt+(j>>2)) + 4g + (j&3)
    for (int s = t; s < 2048; s += NTHR) {
        int lane_s = s & 63, kto = s >> 6;
        int kt = kto & 3, ot = kto >> 2;
        int m = ot * 16 + (lane_s & 15), gs = lane_s >> 4;
        uint32_t f2[4], f3[4];
        #pragma unroll
        for (int jj = 0; jj < 4; ++jj) {
            int k = 16 * (2 * kt + (jj >> 1)) + 4 * gs + 2 * (jj & 1);
            f2[jj] = (uint32_t)f2bf(w2g[k * HID + m] * SCALE)
                   | ((uint32_t)f2bf(w2g[(k + 1) * HID + m] * SCALE) << 16);
            f3[jj] = (uint32_t)f2bf(w3g[k * HID + m] * SCALE)
                   | ((uint32_t)f2bf(w3g[(k + 1) * HID + m] * SCALE) << 16);
        }
        *(u32x4*)&S.w2f[s * 4] = (u32x4){f2[0], f2[1], f2[2], f2[3]};
        *(u32x4*)&S.w3f[s * 4] = (u32x4){f3[0], f3[1], f3[2], f3[3]};
    }
    // ---- stage compact W1: [ot*16+ln] -> {W1[0..1][m], W1[2..3][m]} ----
    if (t < 128) {
        int ot = t >> 4, lns = t & 15;
        int m = ot * 16 + lns;
        S.w1c[t * 2]     = (uint32_t)f2bf(w1g[0 * HID + m] * SCALE)
                         | ((uint32_t)f2bf(w1g[1 * HID + m] * SCALE) << 16);
        S.w1c[t * 2 + 1] = (uint32_t)f2bf(w1g[2 * HID + m] * SCALE)
                         | ((uint32_t)f2bf(w1g[3 * HID + m] * SCALE) << 16);
    }
    // ---- stage W4^T A-frags -> LDS [kt*64+lane], phi-permuted k ----
    if (t < 256) {
        int lane_s = t & 63, kt = t >> 6;
        int lns = lane_s & 15, gs = lane_s >> 4;
        uint32_t f[4];
        #pragma unroll
        for (int jj = 0; jj < 4; ++jj) {
            int k0 = 16 * (2 * kt + (jj >> 1)) + 4 * gs + 2 * (jj & 1);
            uint32_t lo = (lns < 4) ? (uint32_t)f2bf(w4g[k0 * 4 + lns]) : 0u;
            uint32_t hi = (lns < 4) ? (uint32_t)f2bf(w4g[(k0 + 1) * 4 + lns]) : 0u;
            f[jj] = lo | (hi << 16);
        }
        *(u32x4*)&S.w4l[t * 4] = (u32x4){f[0], f[1], f[2], f[3]};
    }
    if (t < HID) {
        S.b1[t] = b1g[t] * SCALE;
        S.b2[t] = b2g[t] * SCALE;
        S.b3[t] = b3g[t] * SCALE;
    }
    __syncthreads();   // the ONLY block-wide barrier

    for (int ch = 0; ch < NCH; ++ch) {
        const int base = ((blk * NW + w) * NCH + ch) * 32;
        // X0 of owner rows (all lanes load; only g==0 values matter)
        f32x4 XA0 = *(const f32x4*)&x0g[((base + ln) >> 2) * 4];
        f32x4 XB0 = *(const f32x4*)&x0g[((base + 16 + ln) >> 2) * 4];
        f32x4 XA = XA0, XB = XB0;
        float* kkw = &S.kk[w * 128];

        #pragma unroll 1
        for (int it = 0; it < NITER; ++it) {
            // ---- anti-hoist: opaque zero, re-defined every iteration ----
            uint32_t zz = 0;
            asm volatile("" : "+v"(zz));
            zz &= ~3u;   // multiple of 4 u32 = 16B: aligns b128 and b64 reads

            // ---- X -> B-frags (k=0..3 real; non-owner slots hit zero weights)
            FragU xa, xb;
            xa.u[0] = owner ? pk2(XA[0], XA[1]) : 0u;
            xa.u[1] = owner ? pk2(XA[2], XA[3]) : 0u;
            xa.u[2] = 0u; xa.u[3] = 0u;
            xb.u[0] = owner ? pk2(XB[0], XB[1]) : 0u;
            xb.u[1] = owner ? pk2(XB[2], XB[3]) : 0u;
            xb.u[2] = 0u; xb.u[3] = 0u;

            // ---- L1: compact-W1 frags (nonzero only on g==0) -> MFMA -> pack
            bf16x8 bfrA[4], bfrB[4];
            #pragma unroll
            for (int op = 0; op < 4; ++op) {
                f32x4 b0 = *(const f32x4*)&S.b1[(2 * op) * 16 + 4 * g + zz];
                f32x4 b1 = *(const f32x4*)&S.b1[(2 * op + 1) * 16 + 4 * g + zz];
                u32x2 c0 = *(const u32x2*)&S.w1c[((2 * op) * 16 + ln) * 2 + zz];
                u32x2 c1 = *(const u32x2*)&S.w1c[((2 * op + 1) * 16 + ln) * 2 + zz];
                FragU w0f, w1f;
                w0f.u[0] = owner ? c0.x : 0u; w0f.u[1] = owner ? c0.y : 0u;
                w0f.u[2] = 0u; w0f.u[3] = 0u;
                w1f.u[0] = owner ? c1.x : 0u; w1f.u[1] = owner ? c1.y : 0u;
                w1f.u[2] = 0u; w1f.u[3] = 0u;
                f32x4 a0A = __builtin_amdgcn_mfma_f32_16x16x32_bf16(w0f.v, xa.v, b0, 0, 0, 0);
                f32x4 a0B = __builtin_amdgcn_mfma_f32_16x16x32_bf16(w0f.v, xb.v, b0, 0, 0, 0);
                f32x4 a1A = __builtin_amdgcn_mfma_f32_16x16x32_bf16(w1f.v, xa.v, b1, 0, 0, 0);
                f32x4 a1B = __builtin_amdgcn_mfma_f32_16x16x32_bf16(w1f.v, xb.v, b1, 0, 0, 0);
                bfrA[op] = pack2(a0A, a1A);
                bfrB[op] = pack2(a0B, a1B);
            }

            // ---- L2, L3 (register-resident chain, weights streamed) ----
            dense_reg(S.w2f, S.b2, bfrA, bfrB, lane, g, zz);
            dense_reg(S.w3f, S.b3, bfrA, bfrB, lane, g, zz);

            // ---- L4 + K + X update (W4 frags from LDS) ----
            f32x4 kA = {0.f, 0.f, 0.f, 0.f}, kB = {0.f, 0.f, 0.f, 0.f};
            __builtin_amdgcn_s_setprio(1);
            #pragma unroll
            for (int kt = 0; kt < 4; ++kt) {
                bf16x8 wfr = *(const bf16x8*)&S.w4l[(kt * 64 + lane) * 4 + zz];
                kA = __builtin_amdgcn_mfma_f32_16x16x32_bf16(wfr, bfrA[kt], kA, 0, 0, 0);
                kB = __builtin_amdgcn_mfma_f32_16x16x32_bf16(wfr, bfrB[kt], kB, 0, 0, 0);
            }
            __builtin_amdgcn_s_setprio(0);
            // owner lanes (g==0) hold K[row][0..3]; kv written to LDS each
            // iter (last one persists) so it's not live across iterations.
            {
                float h0 = kA[0] + B40, h1 = kA[1] + B41;
                float h2 = kA[2] + B42, h3 = kA[3] + B43;
                f32x4 kvA = (f32x4){-L0 * h2 - L1v * XA[2], -L0 * h3 - L1v * XA[3],
                                     L2v * h0 + L3v * XA[0],  L2v * h1 + L3v * XA[1]};
                h0 = kB[0] + B40; h1 = kB[1] + B41;
                h2 = kB[2] + B42; h3 = kB[3] + B43;
                f32x4 kvB = (f32x4){-L0 * h2 - L1v * XB[2], -L0 * h3 - L1v * XB[3],
                                     L2v * h0 + L3v * XB[0],  L2v * h1 + L3v * XB[1]};
                if (owner) {
                    *(f32x4*)&kkw[ln * 4]        = kvA;
                    *(f32x4*)&kkw[(16 + ln) * 4] = kvB;
                }
                #pragma unroll
                for (int c = 0; c < 4; ++c) {
                    float sA = kvA[0] * A[c] + kvA[1] * A[4 + c]
                             + kvA[2] * A[8 + c] + kvA[3] * A[12 + c];
                    float sB = kvB[0] * A[c] + kvB[1] * A[4 + c]
                             + kvB[2] * A[8 + c] + kvB[3] * A[12 + c];
                    XA[c] = fmaf(DT, sA, XA0[c]);
                    XB[c] = fmaf(DT, sB, XB0[c]);
                }
            }
        }

        // ---- final combine via per-wave kk scratch ----
        // per-wave in-order DS + compiler lgkmcnt make the reads safe
        if (lane < 32) {
            int bl_ = lane >> 2, i = lane & 3;
            float s = BE0 * kkw[(bl_ * 4 + 0) * 4 + i]
                    + BE1 * kkw[(bl_ * 4 + 1) * 4 + i]
                    + BE2 * kkw[(bl_ * 4 + 2) * 4 + i]
                    + BE3 * kkw[(bl_ * 4 + 3) * 4 + i];
            int idx = base + lane;
            outg[idx] = x0g[idx] + DT * s;
        }
    }
}

extern "C" void kernel_launch(void* const* d_in, const int* in_sizes, int n_in,
                              void* d_out, int out_size, void* d_ws, size_t ws_size,
                              hipStream_t stream) {
    (void)in_sizes; (void)n_in; (void)d_ws; (void)ws_size; (void)out_size;

    dim3 grid(NBLK);    // 2 blocks/CU (80.4 KB x2 = 157 KB LDS), 8 waves/SIMD
    dim3 block(NTHR);

    pinn_irk_reg<<<grid, block, 0, stream>>>(
        (const float*)d_in[0],
        (const float*)d_in[1],  (const float*)d_in[2],
        (const float*)d_in[3],  (const float*)d_in[4],
        (const float*)d_in[5],  (const float*)d_in[6],
        (const float*)d_in[7],  (const float*)d_in[8],
        (const float*)d_in[9],  (const float*)d_in[10],
        (const float*)d_in[11], (const float*)d_in[12],
        (const float*)d_in[13], (const float*)d_in[14],
        (float*)d_out);
}